// Round 4
// baseline (6927.501 us; speedup 1.0000x reference)
//
#include <hip/hip_runtime.h>

typedef unsigned short u16;
typedef unsigned int u32;
typedef unsigned long long u64;
typedef __attribute__((ext_vector_type(8))) short bf16x8;
typedef __attribute__((ext_vector_type(8))) unsigned short u16x8;
typedef __attribute__((ext_vector_type(4))) float f32x4;

// Problem dims: B=128, T=256, D=512, U=1024, G=4U=4096, C=10
#define TC 32
#define NCHUNK 8

static __device__ __forceinline__ u16 f2bf(float x) {
  union { float f; u32 u; } v; v.f = x;
  u32 r = v.u + 0x7fffu + ((v.u >> 16) & 1u);   // round-to-nearest-even
  return (u16)(r >> 16);
}
static __device__ __forceinline__ float bf2f(u16 h) {
  union { u32 u; float f; } v; v.u = ((u32)h) << 16;
  return v.f;
}
static __device__ __forceinline__ float sigm(float x) {
  return 1.0f / (1.0f + __expf(-x));
}
static __device__ __forceinline__ void gload_lds16(const u16* g, u16* l) {
  __builtin_amdgcn_global_load_lds(
      (const __attribute__((address_space(1))) void*)g,
      (__attribute__((address_space(3))) void*)l, 16, 0, 0);
}

// ---------------- prep: x [B,T,D] f32 -> x_hi/x_lo bf16 [T,B,D] ----------------
__global__ __launch_bounds__(256) void conv_x_kernel(const float* __restrict__ x,
                                                     u16* __restrict__ xh,
                                                     u16* __restrict__ xl) {
  int idx = blockIdx.x * 256 + threadIdx.x;
  size_t i8 = (size_t)idx * 8;
  int b = (int)(i8 >> 17);
  int r = (int)(i8 & 131071);
  int t = r >> 9;
  int d = r & 511;
  const f32x4* s = (const f32x4*)(x + i8);
  f32x4 v0 = s[0], v1 = s[1];
  u16x8 vh, vl;
#pragma unroll
  for (int j = 0; j < 8; ++j) {
    float v = (j < 4) ? v0[j] : v1[j - 4];
    u16 h = f2bf(v);
    vh[j] = h;
    vl[j] = f2bf(v - bf2f(h));
  }
  size_t o = ((size_t)(t * 128 + b)) * 512 + d;
  *(u16x8*)(xh + o) = vh;
  *(u16x8*)(xl + o) = vl;
}

// ------------- prep: weight [K,4096] f32 -> [4096,K] bf16 hi/lo (transposed) -------------
__global__ __launch_bounds__(256) void tsplit_kernel(const float* __restrict__ w,
                                                     u16* __restrict__ oh,
                                                     u16* __restrict__ ol, int K) {
  int idx = blockIdx.x * 256 + threadIdx.x;
  int d = idx >> 10;
  int g4 = (idx & 1023) * 4;
  f32x4 v = *(const f32x4*)(w + (size_t)d * 4096 + g4);
#pragma unroll
  for (int j = 0; j < 4; ++j) {
    int g = g4 + j;
    u16 h = f2bf(v[j]);
    oh[(size_t)g * K + d] = h;
    ol[(size_t)g * K + d] = f2bf(v[j] - bf2f(h));
  }
}

// ------------- GEMM1 (per chunk): xz[(t-c*TC)*128+b][g] = x @ kernel + bias -------------
__global__ __launch_bounds__(256) void gemm1_kernel(const u16* __restrict__ xh,
                                                    const u16* __restrict__ xl,
                                                    const u16* __restrict__ kh,
                                                    const u16* __restrict__ kl,
                                                    const float* __restrict__ bias,
                                                    float* __restrict__ xz, int c) {
  __shared__ u16 Ah[4096], Al[4096], Bh[4096], Bl[4096];
  const int tid = threadIdx.x;
  const int w = tid >> 6, l = tid & 63;
  const int m0w = blockIdx.y * 128;
  const int m0g = c * 4096 + m0w;
  const int n0 = blockIdx.x * 128;
  const int wr = w >> 1, wc = w & 1;
  const int srow = l >> 2, schunk = l & 3;
  const int fr = l & 15, fc = l >> 4;

  f32x4 acc[4][4];
#pragma unroll
  for (int a = 0; a < 4; ++a)
#pragma unroll
    for (int b = 0; b < 4; ++b) acc[a][b] = (f32x4){0.f, 0.f, 0.f, 0.f};

  for (int kt = 0; kt < 16; ++kt) {
    const int koff = kt * 32 + schunk * 8;
#pragma unroll
    for (int i = 0; i < 8; ++i) {
      const int q = w + i * 4;
      const int buf = q >> 3, ch = q & 7;
      const size_t ro = (size_t)(ch * 16 + srow);
      if (buf == 0)      gload_lds16(xh + (m0g + ro) * 512 + koff, Ah + ch * 512);
      else if (buf == 1) gload_lds16(xl + (m0g + ro) * 512 + koff, Al + ch * 512);
      else if (buf == 2) gload_lds16(kh + (n0 + ro) * 512 + koff, Bh + ch * 512);
      else               gload_lds16(kl + (n0 + ro) * 512 + koff, Bl + ch * 512);
    }
    __syncthreads();

    bf16x8 a_h[4], a_l[4], b_h[4], b_l[4];
#pragma unroll
    for (int mf = 0; mf < 4; ++mf) {
      int row = wr * 64 + mf * 16 + fr;
      a_h[mf] = *(const bf16x8*)(Ah + row * 32 + fc * 8);
      a_l[mf] = *(const bf16x8*)(Al + row * 32 + fc * 8);
    }
#pragma unroll
    for (int nf = 0; nf < 4; ++nf) {
      int col = wc * 64 + nf * 16 + fr;
      b_h[nf] = *(const bf16x8*)(Bh + col * 32 + fc * 8);
      b_l[nf] = *(const bf16x8*)(Bl + col * 32 + fc * 8);
    }
#pragma unroll
    for (int mf = 0; mf < 4; ++mf)
#pragma unroll
      for (int nf = 0; nf < 4; ++nf) {
        acc[mf][nf] = __builtin_amdgcn_mfma_f32_16x16x32_bf16(a_h[mf], b_h[nf], acc[mf][nf], 0, 0, 0);
        acc[mf][nf] = __builtin_amdgcn_mfma_f32_16x16x32_bf16(a_h[mf], b_l[nf], acc[mf][nf], 0, 0, 0);
        acc[mf][nf] = __builtin_amdgcn_mfma_f32_16x16x32_bf16(a_l[mf], b_h[nf], acc[mf][nf], 0, 0, 0);
      }
    __syncthreads();
  }

#pragma unroll
  for (int nf = 0; nf < 4; ++nf) {
    const int col = n0 + wc * 64 + nf * 16 + fr;
    const float bv = bias[col];
#pragma unroll
    for (int mf = 0; mf < 4; ++mf) {
      const int rw = m0w + wr * 64 + mf * 16 + fc * 4;
#pragma unroll
      for (int rg = 0; rg < 4; ++rg)
        xz[(size_t)(rw + rg) * 4096 + col] = acc[mf][nf][rg] + bv;
    }
  }
}

// ------------- init: zero the barrier counter -------------
__global__ void init_kernel(u32* bar) {
  if (threadIdx.x == 0 && blockIdx.x == 0) *bar = 0u;
}

// ------------- persistent LSTM scan, one chunk of TC steps -------------
// 256 blocks (1/CU). Block: mi = blk>>7 (64 batch rows), ui = blk&127 (8 U-cols).
// R slice in LDS (staged once per chunk). c-state in registers. h exchanged via
// packed u32 (hi<<16|lo) with relaxed AGENT-scope atomics (sc0 sc1 -> MALL coherent
// point, no cache flushes). Grid barrier: 1 relaxed atomicAdd per block + thread0
// spin; monotonic target = (global_step+1)*256.
__global__ __launch_bounds__(256, 1) void lstm_scan_kernel(
    const float* __restrict__ xz,
    const u16* __restrict__ rwh, const u16* __restrict__ rwl,
    u32* __restrict__ h32, float* __restrict__ cf,
    u32* __restrict__ bar, int c) {
  __shared__ u16 Rh[32768];   // [nf 2][ks 32][lane 64][8] = 64KB
  __shared__ u16 Rl[32768];   // 64KB
  const int tid = threadIdx.x;
  const int w = tid >> 6, l = tid & 63;
  const int blk = blockIdx.x;
  const int mi = blk >> 7, ui = blk & 127;

  // stage R fragments once per chunk
  for (int gidx = tid; gidx < 4096; gidx += 256) {
    const int lr = gidx & 63;
    const int ks = (gidx >> 6) & 31;
    const int nf = gidx >> 11;
    const int cc = lr & 15;
    const int kb = ks * 32 + ((lr >> 4) << 3);
    const int gate = nf * 2 + (cc >> 3);
    const size_t gcol = (size_t)(gate * 1024 + ui * 8 + (cc & 7));
    *(u16x8*)(Rh + gidx * 8) = *(const u16x8*)(rwh + gcol * 1024 + kb);
    *(u16x8*)(Rl + gidx * 8) = *(const u16x8*)(rwl + gcol * 1024 + kb);
  }

  const int fr = l & 15, fc = l >> 4;
  const int arow = mi * 64 + w * 16 + fr;        // A-fragment row (batch index)
  const int crow = mi * 64 + w * 16 + fc * 4;    // C rows base (batch index)
  const int uu = ui * 8 + (fr & 7);
  const int gcol0 = ((fr >> 3) ? 1024 : 0) + uu;      // i or f column
  const int gcol1 = ((fr >> 3) ? 3072 : 2048) + uu;   // g or o column

  float cs[4] = {0.f, 0.f, 0.f, 0.f};
  if (c && fr < 8) {
#pragma unroll
    for (int rg = 0; rg < 4; ++rg) cs[rg] = cf[(size_t)(crow + rg) * 1024 + uu];
  }
  __syncthreads();

  for (int tc = 0; tc < TC; ++tc) {
    const int t = c * TC + tc;
    f32x4 a0 = (f32x4){0.f, 0.f, 0.f, 0.f};
    f32x4 a1 = (f32x4){0.f, 0.f, 0.f, 0.f};
    if (t) {   // global t=0: h=0, z = xz only
      const u32* hp = h32 + ((size_t)(t & 1) << 17) + (size_t)arow * 1024 + fc * 8;
#pragma unroll 4
      for (int ks = 0; ks < 32; ++ks) {
        const u64* hq = (const u64*)(hp + ks * 32);
        u64 q0 = __hip_atomic_load(hq + 0, __ATOMIC_RELAXED, __HIP_MEMORY_SCOPE_AGENT);
        u64 q1 = __hip_atomic_load(hq + 1, __ATOMIC_RELAXED, __HIP_MEMORY_SCOPE_AGENT);
        u64 q2 = __hip_atomic_load(hq + 2, __ATOMIC_RELAXED, __HIP_MEMORY_SCOPE_AGENT);
        u64 q3 = __hip_atomic_load(hq + 3, __ATOMIC_RELAXED, __HIP_MEMORY_SCOPE_AGENT);
        u32 P0 = (u32)q0, P1 = (u32)(q0 >> 32);
        u32 P2 = (u32)q1, P3 = (u32)(q1 >> 32);
        u32 P4 = (u32)q2, P5 = (u32)(q2 >> 32);
        u32 P6 = (u32)q3, P7 = (u32)(q3 >> 32);
        union { u32 wv[4]; bf16x8 v; } uh, ul;
        uh.wv[0] = __builtin_amdgcn_perm(P1, P0, 0x07060302u);
        ul.wv[0] = __builtin_amdgcn_perm(P1, P0, 0x05040100u);
        uh.wv[1] = __builtin_amdgcn_perm(P3, P2, 0x07060302u);
        ul.wv[1] = __builtin_amdgcn_perm(P3, P2, 0x05040100u);
        uh.wv[2] = __builtin_amdgcn_perm(P5, P4, 0x07060302u);
        ul.wv[2] = __builtin_amdgcn_perm(P5, P4, 0x05040100u);
        uh.wv[3] = __builtin_amdgcn_perm(P7, P6, 0x07060302u);
        ul.wv[3] = __builtin_amdgcn_perm(P7, P6, 0x05040100u);
        bf16x8 b0h = *(const bf16x8*)(Rh + (ks * 64 + l) * 8);
        bf16x8 b0l = *(const bf16x8*)(Rl + (ks * 64 + l) * 8);
        bf16x8 b1h = *(const bf16x8*)(Rh + ((32 + ks) * 64 + l) * 8);
        bf16x8 b1l = *(const bf16x8*)(Rl + ((32 + ks) * 64 + l) * 8);
        a0 = __builtin_amdgcn_mfma_f32_16x16x32_bf16(uh.v, b0h, a0, 0, 0, 0);
        a0 = __builtin_amdgcn_mfma_f32_16x16x32_bf16(uh.v, b0l, a0, 0, 0, 0);
        a0 = __builtin_amdgcn_mfma_f32_16x16x32_bf16(ul.v, b0h, a0, 0, 0, 0);
        a1 = __builtin_amdgcn_mfma_f32_16x16x32_bf16(uh.v, b1h, a1, 0, 0, 0);
        a1 = __builtin_amdgcn_mfma_f32_16x16x32_bf16(uh.v, b1l, a1, 0, 0, 0);
        a1 = __builtin_amdgcn_mfma_f32_16x16x32_bf16(ul.v, b1h, a1, 0, 0, 0);
      }
    }
    const float* xzt = xz + ((size_t)tc << 19);  // tc * 128 * 4096
    float z0[4], z1[4];
#pragma unroll
    for (int rg = 0; rg < 4; ++rg) {
      z0[rg] = a0[rg] + xzt[(size_t)(crow + rg) * 4096 + gcol0];
      z1[rg] = a1[rg] + xzt[(size_t)(crow + rg) * 4096 + gcol1];
    }
    u32* wp = h32 + ((size_t)((t + 1) & 1) << 17);
#pragma unroll
    for (int rg = 0; rg < 4; ++rg) {
      float p0 = __shfl_xor(z0[rg], 8, 64);      // pair (i,f) / (g,o) lanes
      float p1 = __shfl_xor(z1[rg], 8, 64);
      if (fr < 8) {
        float ig = sigm(z0[rg]);
        float fg = sigm(p0);
        float gg = tanhf(z1[rg]);
        float og = sigm(p1);
        float cn = fg * cs[rg] + ig * gg;
        cs[rg] = cn;
        float hv = og * tanhf(cn);
        u16 hi = f2bf(hv);
        u16 lo = f2bf(hv - bf2f(hi));
        u32 P = ((u32)hi << 16) | (u32)lo;
        __hip_atomic_store(wp + (size_t)(crow + rg) * 1024 + uu, P,
                           __ATOMIC_RELAXED, __HIP_MEMORY_SCOPE_AGENT);
      }
    }
    // ---- lean grid barrier: drain stores, arrive, spin (thread 0), release ----
    asm volatile("s_waitcnt vmcnt(0)" ::: "memory");
    __syncthreads();
    if (tid == 0) {
      __hip_atomic_fetch_add(bar, 1u, __ATOMIC_RELAXED, __HIP_MEMORY_SCOPE_AGENT);
      const u32 target = (u32)(t + 1) * 256u;
      int guard = 0;
      while (__hip_atomic_load(bar, __ATOMIC_RELAXED, __HIP_MEMORY_SCOPE_AGENT) < target &&
             guard < (1 << 20)) {
        ++guard;
        __builtin_amdgcn_s_sleep(1);
      }
    }
    __syncthreads();
  }

  if (fr < 8) {
#pragma unroll
    for (int rg = 0; rg < 4; ++rg) cf[(size_t)(crow + rg) * 1024 + uu] = cs[rg];
  }
}

// ------------- classifier + softmax: one block per batch row -------------
__global__ __launch_bounds__(256) void cls_kernel(const u32* __restrict__ h32,
                                                  const float* __restrict__ wcls,
                                                  const float* __restrict__ bcls,
                                                  float* __restrict__ out) {
  __shared__ float red[2560];
  const int tid = threadIdx.x;
  const int row = blockIdx.x;
  float acc[10];
#pragma unroll
  for (int cc = 0; cc < 10; ++cc) acc[cc] = 0.f;
  const u32* hr = h32 + (size_t)row * 1024;      // h(256) lives in buffer 0
  const int k0 = tid * 4;
  for (int k = k0; k < k0 + 4; ++k) {
    u32 P = hr[k];
    float hv = bf2f((u16)(P >> 16)) + bf2f((u16)(P & 0xffffu));
#pragma unroll
    for (int cc = 0; cc < 10; ++cc) acc[cc] += hv * wcls[(size_t)k * 10 + cc];
  }
#pragma unroll
  for (int cc = 0; cc < 10; ++cc) red[tid * 10 + cc] = acc[cc];
  __syncthreads();
  for (int s = 128; s >= 1; s >>= 1) {
    if (tid < s) {
#pragma unroll
      for (int cc = 0; cc < 10; ++cc) red[tid * 10 + cc] += red[(tid + s) * 10 + cc];
    }
    __syncthreads();
  }
  if (tid == 0) {
    float lg[10];
    float m = -1e30f;
#pragma unroll
    for (int cc = 0; cc < 10; ++cc) { lg[cc] = red[cc] + bcls[cc]; m = fmaxf(m, lg[cc]); }
    float ssum = 0.f;
#pragma unroll
    for (int cc = 0; cc < 10; ++cc) { lg[cc] = __expf(lg[cc] - m); ssum += lg[cc]; }
    float inv = 1.f / ssum;
#pragma unroll
    for (int cc = 0; cc < 10; ++cc) out[row * 10 + cc] = lg[cc] * inv;
  }
}

// ---------------- host ----------------
extern "C" void kernel_launch(void* const* d_in, const int* in_sizes, int n_in,
                              void* d_out, int out_size, void* d_ws, size_t ws_size,
                              hipStream_t stream) {
  const float* x    = (const float*)d_in[0];
  const float* kern = (const float*)d_in[1];
  const float* rker = (const float*)d_in[2];
  const float* bias = (const float*)d_in[3];
  const float* wcls = (const float*)d_in[4];
  const float* bcls = (const float*)d_in[5];
  float* out = (float*)d_out;
  char* ws = (char*)d_ws;

  // workspace layout (bytes) — total ~160.96 MB (same as round 3 + 4B barrier)
  float* xz = (float*)(ws + 0UL);                 //  67,108,864  xz chunk fp32 [TC][128][4096]
  u16* xh   = (u16*)(ws + 67108864UL);            //  33,554,432  x hi bf16 [T*128][512]
  u16* xl   = (u16*)(ws + 100663296UL);           //  33,554,432
  u16* kh   = (u16*)(ws + 134217728UL);           //   4,194,304  kernel^T hi [4096][512]
  u16* kl   = (u16*)(ws + 138412032UL);           //   4,194,304
  u16* rh   = (u16*)(ws + 142606336UL);           //   8,388,608  R^T hi [4096][1024]
  u16* rl   = (u16*)(ws + 150994944UL);           //   8,388,608
  u32* h32  = (u32*)(ws + 159383552UL);           //   1,048,576  h packed (hi|lo) [2][128][1024]
  float* cf = (float*)(ws + 160432128UL);         //     524,288  c state fp32 [128][1024]
  u32* bar  = (u32*)(ws + 160956416UL);           //           4  barrier counter

  conv_x_kernel<<<8192, 256, 0, stream>>>(x, xh, xl);
  tsplit_kernel<<<2048, 256, 0, stream>>>(kern, kh, kl, 512);
  tsplit_kernel<<<4096, 256, 0, stream>>>(rker, rh, rl, 1024);
  init_kernel<<<1, 64, 0, stream>>>(bar);

  for (int c = 0; c < NCHUNK; ++c) {
    gemm1_kernel<<<dim3(32, 32), 256, 0, stream>>>(xh, xl, kh, kl, bias, xz, c);
    void* sargs[7];
    int cv = c;
    sargs[0] = (void*)&xz;
    sargs[1] = (void*)&rh;
    sargs[2] = (void*)&rl;
    sargs[3] = (void*)&h32;
    sargs[4] = (void*)&cf;
    sargs[5] = (void*)&bar;
    sargs[6] = (void*)&cv;
    hipLaunchCooperativeKernel((const void*)lstm_scan_kernel, dim3(256), dim3(256),
                               sargs, 0u, stream);
  }
  cls_kernel<<<128, 256, 0, stream>>>(h32, wcls, bcls, out);
}

// Round 5
// 5637.761 us; speedup vs baseline: 1.2288x; 1.2288x over previous
//
#include <hip/hip_runtime.h>

typedef unsigned short u16;
typedef unsigned int u32;
typedef unsigned long long u64;
typedef __attribute__((ext_vector_type(8))) short bf16x8;
typedef __attribute__((ext_vector_type(8))) unsigned short u16x8;
typedef __attribute__((ext_vector_type(4))) float f32x4;

// Problem dims: B=128, T=256, D=512, U=1024, G=4U=4096, C=10
#define TC 32
#define NCHUNK 8

static __device__ __forceinline__ u16 f2bf(float x) {
  union { float f; u32 u; } v; v.f = x;
  u32 r = v.u + 0x7fffu + ((v.u >> 16) & 1u);   // round-to-nearest-even
  return (u16)(r >> 16);
}
static __device__ __forceinline__ float bf2f(u16 h) {
  union { u32 u; float f; } v; v.u = ((u32)h) << 16;
  return v.f;
}
static __device__ __forceinline__ float sigm(float x) {
  return 1.0f / (1.0f + __expf(-x));
}
static __device__ __forceinline__ void gload_lds16(const u16* g, u16* l) {
  __builtin_amdgcn_global_load_lds(
      (const __attribute__((address_space(1))) void*)g,
      (__attribute__((address_space(3))) void*)l, 16, 0, 0);
}

// ---------------- prep: x [B,T,D] f32 -> x_hi/x_lo bf16 [T,B,D] ----------------
__global__ __launch_bounds__(256) void conv_x_kernel(const float* __restrict__ x,
                                                     u16* __restrict__ xh,
                                                     u16* __restrict__ xl) {
  int idx = blockIdx.x * 256 + threadIdx.x;
  size_t i8 = (size_t)idx * 8;
  int b = (int)(i8 >> 17);
  int r = (int)(i8 & 131071);
  int t = r >> 9;
  int d = r & 511;
  const f32x4* s = (const f32x4*)(x + i8);
  f32x4 v0 = s[0], v1 = s[1];
  u16x8 vh, vl;
#pragma unroll
  for (int j = 0; j < 8; ++j) {
    float v = (j < 4) ? v0[j] : v1[j - 4];
    u16 h = f2bf(v);
    vh[j] = h;
    vl[j] = f2bf(v - bf2f(h));
  }
  size_t o = ((size_t)(t * 128 + b)) * 512 + d;
  *(u16x8*)(xh + o) = vh;
  *(u16x8*)(xl + o) = vl;
}

// ------------- prep: weight [K,4096] f32 -> [4096,K] bf16 hi/lo (transposed) -------------
__global__ __launch_bounds__(256) void tsplit_kernel(const float* __restrict__ w,
                                                     u16* __restrict__ oh,
                                                     u16* __restrict__ ol, int K) {
  int idx = blockIdx.x * 256 + threadIdx.x;
  int d = idx >> 10;
  int g4 = (idx & 1023) * 4;
  f32x4 v = *(const f32x4*)(w + (size_t)d * 4096 + g4);
#pragma unroll
  for (int j = 0; j < 4; ++j) {
    int g = g4 + j;
    u16 h = f2bf(v[j]);
    oh[(size_t)g * K + d] = h;
    ol[(size_t)g * K + d] = f2bf(v[j] - bf2f(h));
  }
}

// ------------- GEMM1 (per chunk): xz[(t-c*TC)*128+b][g] = x @ kernel + bias -------------
__global__ __launch_bounds__(256) void gemm1_kernel(const u16* __restrict__ xh,
                                                    const u16* __restrict__ xl,
                                                    const u16* __restrict__ kh,
                                                    const u16* __restrict__ kl,
                                                    const float* __restrict__ bias,
                                                    float* __restrict__ xz, int c) {
  __shared__ u16 Ah[4096], Al[4096], Bh[4096], Bl[4096];
  const int tid = threadIdx.x;
  const int w = tid >> 6, l = tid & 63;
  const int m0w = blockIdx.y * 128;
  const int m0g = c * 4096 + m0w;
  const int n0 = blockIdx.x * 128;
  const int wr = w >> 1, wc = w & 1;
  const int srow = l >> 2, schunk = l & 3;
  const int fr = l & 15, fc = l >> 4;

  f32x4 acc[4][4];
#pragma unroll
  for (int a = 0; a < 4; ++a)
#pragma unroll
    for (int b = 0; b < 4; ++b) acc[a][b] = (f32x4){0.f, 0.f, 0.f, 0.f};

  for (int kt = 0; kt < 16; ++kt) {
    const int koff = kt * 32 + schunk * 8;
#pragma unroll
    for (int i = 0; i < 8; ++i) {
      const int q = w + i * 4;
      const int buf = q >> 3, ch = q & 7;
      const size_t ro = (size_t)(ch * 16 + srow);
      if (buf == 0)      gload_lds16(xh + (m0g + ro) * 512 + koff, Ah + ch * 512);
      else if (buf == 1) gload_lds16(xl + (m0g + ro) * 512 + koff, Al + ch * 512);
      else if (buf == 2) gload_lds16(kh + (n0 + ro) * 512 + koff, Bh + ch * 512);
      else               gload_lds16(kl + (n0 + ro) * 512 + koff, Bl + ch * 512);
    }
    __syncthreads();

    bf16x8 a_h[4], a_l[4], b_h[4], b_l[4];
#pragma unroll
    for (int mf = 0; mf < 4; ++mf) {
      int row = wr * 64 + mf * 16 + fr;
      a_h[mf] = *(const bf16x8*)(Ah + row * 32 + fc * 8);
      a_l[mf] = *(const bf16x8*)(Al + row * 32 + fc * 8);
    }
#pragma unroll
    for (int nf = 0; nf < 4; ++nf) {
      int col = wc * 64 + nf * 16 + fr;
      b_h[nf] = *(const bf16x8*)(Bh + col * 32 + fc * 8);
      b_l[nf] = *(const bf16x8*)(Bl + col * 32 + fc * 8);
    }
#pragma unroll
    for (int mf = 0; mf < 4; ++mf)
#pragma unroll
      for (int nf = 0; nf < 4; ++nf) {
        acc[mf][nf] = __builtin_amdgcn_mfma_f32_16x16x32_bf16(a_h[mf], b_h[nf], acc[mf][nf], 0, 0, 0);
        acc[mf][nf] = __builtin_amdgcn_mfma_f32_16x16x32_bf16(a_h[mf], b_l[nf], acc[mf][nf], 0, 0, 0);
        acc[mf][nf] = __builtin_amdgcn_mfma_f32_16x16x32_bf16(a_l[mf], b_h[nf], acc[mf][nf], 0, 0, 0);
      }
    __syncthreads();
  }

#pragma unroll
  for (int nf = 0; nf < 4; ++nf) {
    const int col = n0 + wc * 64 + nf * 16 + fr;
    const float bv = bias[col];
#pragma unroll
    for (int mf = 0; mf < 4; ++mf) {
      const int rw = m0w + wr * 64 + mf * 16 + fc * 4;
#pragma unroll
      for (int rg = 0; rg < 4; ++rg)
        xz[(size_t)(rw + rg) * 4096 + col] = acc[mf][nf][rg] + bv;
    }
  }
}

// ------------- init: zero barrier flags (ws is 0xAA-poisoned before every launch) -------------
__global__ __launch_bounds__(256) void init_kernel(u32* flags) {
  // flags[0..4095] = per-block arrival flags (stride 16 u32 = 64B); flags[4096] = release
  for (int i = threadIdx.x; i <= 4096; i += 256) flags[i] = 0u;
}

// ------------- persistent LSTM scan, one chunk of TC steps -------------
// 256 blocks (1/CU). Block: mi = blk>>7 (64 batch rows), ui = blk&127 (8 U-cols).
// R slice in LDS (staged once per chunk). c-state in registers. h exchanged via
// packed u32 (hi<<16|lo) relaxed agent-scope atomics (write-through to MALL, no
// cache flushes). Grid barrier: contention-free flag array + central release —
// NO read-modify-writes (round-4 profile showed the single atomicAdd counter
// serialized ~256 RMWs/step at the MALL ≈ 16 us/step).
__global__ __launch_bounds__(256, 1) void lstm_scan_kernel(
    const float* __restrict__ xz,
    const u16* __restrict__ rwh, const u16* __restrict__ rwl,
    u32* __restrict__ h32, float* __restrict__ cf,
    u32* __restrict__ flags, int c) {
  __shared__ u16 Rh[32768];   // [nf 2][ks 32][lane 64][8] = 64KB
  __shared__ u16 Rl[32768];   // 64KB
  const int tid = threadIdx.x;
  const int w = tid >> 6, l = tid & 63;
  const int blk = blockIdx.x;
  const int mi = blk >> 7, ui = blk & 127;
  u32* release = flags + 4096;

  // stage R fragments once per chunk
  for (int gidx = tid; gidx < 4096; gidx += 256) {
    const int lr = gidx & 63;
    const int ks = (gidx >> 6) & 31;
    const int nf = gidx >> 11;
    const int cc = lr & 15;
    const int kb = ks * 32 + ((lr >> 4) << 3);
    const int gate = nf * 2 + (cc >> 3);
    const size_t gcol = (size_t)(gate * 1024 + ui * 8 + (cc & 7));
    *(u16x8*)(Rh + gidx * 8) = *(const u16x8*)(rwh + gcol * 1024 + kb);
    *(u16x8*)(Rl + gidx * 8) = *(const u16x8*)(rwl + gcol * 1024 + kb);
  }

  const int fr = l & 15, fc = l >> 4;
  const int arow = mi * 64 + w * 16 + fr;        // A-fragment row (batch index)
  const int crow = mi * 64 + w * 16 + fc * 4;    // C rows base (batch index)
  const int uu = ui * 8 + (fr & 7);
  const int gcol0 = ((fr >> 3) ? 1024 : 0) + uu;      // i or f column
  const int gcol1 = ((fr >> 3) ? 3072 : 2048) + uu;   // g or o column

  float cs[4] = {0.f, 0.f, 0.f, 0.f};
  if (c && fr < 8) {
#pragma unroll
    for (int rg = 0; rg < 4; ++rg) cs[rg] = cf[(size_t)(crow + rg) * 1024 + uu];
  }
  __syncthreads();

  for (int tc = 0; tc < TC; ++tc) {
    const int t = c * TC + tc;
    f32x4 a0 = (f32x4){0.f, 0.f, 0.f, 0.f};
    f32x4 a1 = (f32x4){0.f, 0.f, 0.f, 0.f};
    if (t) {   // global t=0: h=0, z = xz only
      const u32* hp = h32 + ((size_t)(t & 1) << 17) + (size_t)arow * 1024 + fc * 8;
#pragma unroll 4
      for (int ks = 0; ks < 32; ++ks) {
        const u64* hq = (const u64*)(hp + ks * 32);
        u64 q0 = __hip_atomic_load(hq + 0, __ATOMIC_RELAXED, __HIP_MEMORY_SCOPE_AGENT);
        u64 q1 = __hip_atomic_load(hq + 1, __ATOMIC_RELAXED, __HIP_MEMORY_SCOPE_AGENT);
        u64 q2 = __hip_atomic_load(hq + 2, __ATOMIC_RELAXED, __HIP_MEMORY_SCOPE_AGENT);
        u64 q3 = __hip_atomic_load(hq + 3, __ATOMIC_RELAXED, __HIP_MEMORY_SCOPE_AGENT);
        u32 P0 = (u32)q0, P1 = (u32)(q0 >> 32);
        u32 P2 = (u32)q1, P3 = (u32)(q1 >> 32);
        u32 P4 = (u32)q2, P5 = (u32)(q2 >> 32);
        u32 P6 = (u32)q3, P7 = (u32)(q3 >> 32);
        union { u32 wv[4]; bf16x8 v; } uh, ul;
        uh.wv[0] = __builtin_amdgcn_perm(P1, P0, 0x07060302u);
        ul.wv[0] = __builtin_amdgcn_perm(P1, P0, 0x05040100u);
        uh.wv[1] = __builtin_amdgcn_perm(P3, P2, 0x07060302u);
        ul.wv[1] = __builtin_amdgcn_perm(P3, P2, 0x05040100u);
        uh.wv[2] = __builtin_amdgcn_perm(P5, P4, 0x07060302u);
        ul.wv[2] = __builtin_amdgcn_perm(P5, P4, 0x05040100u);
        uh.wv[3] = __builtin_amdgcn_perm(P7, P6, 0x07060302u);
        ul.wv[3] = __builtin_amdgcn_perm(P7, P6, 0x05040100u);
        bf16x8 b0h = *(const bf16x8*)(Rh + (ks * 64 + l) * 8);
        bf16x8 b0l = *(const bf16x8*)(Rl + (ks * 64 + l) * 8);
        bf16x8 b1h = *(const bf16x8*)(Rh + ((32 + ks) * 64 + l) * 8);
        bf16x8 b1l = *(const bf16x8*)(Rl + ((32 + ks) * 64 + l) * 8);
        a0 = __builtin_amdgcn_mfma_f32_16x16x32_bf16(uh.v, b0h, a0, 0, 0, 0);
        a0 = __builtin_amdgcn_mfma_f32_16x16x32_bf16(uh.v, b0l, a0, 0, 0, 0);
        a0 = __builtin_amdgcn_mfma_f32_16x16x32_bf16(ul.v, b0h, a0, 0, 0, 0);
        a1 = __builtin_amdgcn_mfma_f32_16x16x32_bf16(uh.v, b1h, a1, 0, 0, 0);
        a1 = __builtin_amdgcn_mfma_f32_16x16x32_bf16(uh.v, b1l, a1, 0, 0, 0);
        a1 = __builtin_amdgcn_mfma_f32_16x16x32_bf16(ul.v, b1h, a1, 0, 0, 0);
      }
    }
    const float* xzt = xz + ((size_t)tc << 19);  // tc * 128 * 4096
    float z0[4], z1[4];
#pragma unroll
    for (int rg = 0; rg < 4; ++rg) {
      z0[rg] = a0[rg] + xzt[(size_t)(crow + rg) * 4096 + gcol0];
      z1[rg] = a1[rg] + xzt[(size_t)(crow + rg) * 4096 + gcol1];
    }
    u32* wp = h32 + ((size_t)((t + 1) & 1) << 17);
#pragma unroll
    for (int rg = 0; rg < 4; ++rg) {
      float p0 = __shfl_xor(z0[rg], 8, 64);      // pair (i,f) / (g,o) lanes
      float p1 = __shfl_xor(z1[rg], 8, 64);
      if (fr < 8) {
        float ig = sigm(z0[rg]);
        float fg = sigm(p0);
        float gg = tanhf(z1[rg]);
        float og = sigm(p1);
        float cn = fg * cs[rg] + ig * gg;
        cs[rg] = cn;
        float hv = og * tanhf(cn);
        u16 hi = f2bf(hv);
        u16 lo = f2bf(hv - bf2f(hi));
        u32 P = ((u32)hi << 16) | (u32)lo;
        __hip_atomic_store(wp + (size_t)(crow + rg) * 1024 + uu, P,
                           __ATOMIC_RELAXED, __HIP_MEMORY_SCOPE_AGENT);
      }
    }
    // ---- contention-free grid barrier (monotonic, no RMW) ----
    const u32 tgt = (u32)(t + 1);
    asm volatile("s_waitcnt vmcnt(0)" ::: "memory");   // h stores reached MALL
    __syncthreads();
    if (blk == 0) {
      if (tid == 0)
        __hip_atomic_store(flags + 0, tgt, __ATOMIC_RELAXED, __HIP_MEMORY_SCOPE_AGENT);
      // 256 threads each poll one block's flag (distinct 64B lines)
      for (int g = 0; g < (1 << 18); ++g) {
        if (__hip_atomic_load(flags + tid * 16, __ATOMIC_RELAXED,
                              __HIP_MEMORY_SCOPE_AGENT) >= tgt) break;
      }
      __syncthreads();
      if (tid == 0)
        __hip_atomic_store(release, tgt, __ATOMIC_RELAXED, __HIP_MEMORY_SCOPE_AGENT);
    } else {
      if (tid == 0) {
        __hip_atomic_store(flags + blk * 16, tgt, __ATOMIC_RELAXED,
                           __HIP_MEMORY_SCOPE_AGENT);
        for (int g = 0; g < (1 << 18); ++g) {
          if (__hip_atomic_load(release, __ATOMIC_RELAXED,
                                __HIP_MEMORY_SCOPE_AGENT) >= tgt) break;
          __builtin_amdgcn_s_sleep(1);
        }
      }
      __syncthreads();
    }
  }

  if (fr < 8) {
#pragma unroll
    for (int rg = 0; rg < 4; ++rg) cf[(size_t)(crow + rg) * 1024 + uu] = cs[rg];
  }
}

// ------------- classifier + softmax: one block per batch row -------------
__global__ __launch_bounds__(256) void cls_kernel(const u32* __restrict__ h32,
                                                  const float* __restrict__ wcls,
                                                  const float* __restrict__ bcls,
                                                  float* __restrict__ out) {
  __shared__ float red[2560];
  const int tid = threadIdx.x;
  const int row = blockIdx.x;
  float acc[10];
#pragma unroll
  for (int cc = 0; cc < 10; ++cc) acc[cc] = 0.f;
  const u32* hr = h32 + (size_t)row * 1024;      // h(256) lives in buffer 0
  const int k0 = tid * 4;
  for (int k = k0; k < k0 + 4; ++k) {
    u32 P = hr[k];
    float hv = bf2f((u16)(P >> 16)) + bf2f((u16)(P & 0xffffu));
#pragma unroll
    for (int cc = 0; cc < 10; ++cc) acc[cc] += hv * wcls[(size_t)k * 10 + cc];
  }
#pragma unroll
  for (int cc = 0; cc < 10; ++cc) red[tid * 10 + cc] = acc[cc];
  __syncthreads();
  for (int s = 128; s >= 1; s >>= 1) {
    if (tid < s) {
#pragma unroll
      for (int cc = 0; cc < 10; ++cc) red[tid * 10 + cc] += red[(tid + s) * 10 + cc];
    }
    __syncthreads();
  }
  if (tid == 0) {
    float lg[10];
    float m = -1e30f;
#pragma unroll
    for (int cc = 0; cc < 10; ++cc) { lg[cc] = red[cc] + bcls[cc]; m = fmaxf(m, lg[cc]); }
    float ssum = 0.f;
#pragma unroll
    for (int cc = 0; cc < 10; ++cc) { lg[cc] = __expf(lg[cc] - m); ssum += lg[cc]; }
    float inv = 1.f / ssum;
#pragma unroll
    for (int cc = 0; cc < 10; ++cc) out[row * 10 + cc] = lg[cc] * inv;
  }
}

// ---------------- host ----------------
extern "C" void kernel_launch(void* const* d_in, const int* in_sizes, int n_in,
                              void* d_out, int out_size, void* d_ws, size_t ws_size,
                              hipStream_t stream) {
  const float* x    = (const float*)d_in[0];
  const float* kern = (const float*)d_in[1];
  const float* rker = (const float*)d_in[2];
  const float* bias = (const float*)d_in[3];
  const float* wcls = (const float*)d_in[4];
  const float* bcls = (const float*)d_in[5];
  float* out = (float*)d_out;
  char* ws = (char*)d_ws;

  // workspace layout (bytes) — total ~161.0 MB
  float* xz = (float*)(ws + 0UL);                 //  67,108,864  xz chunk fp32 [TC][128][4096]
  u16* xh   = (u16*)(ws + 67108864UL);            //  33,554,432  x hi bf16 [T*128][512]
  u16* xl   = (u16*)(ws + 100663296UL);           //  33,554,432
  u16* kh   = (u16*)(ws + 134217728UL);           //   4,194,304  kernel^T hi [4096][512]
  u16* kl   = (u16*)(ws + 138412032UL);           //   4,194,304
  u16* rh   = (u16*)(ws + 142606336UL);           //   8,388,608  R^T hi [4096][1024]
  u16* rl   = (u16*)(ws + 150994944UL);           //   8,388,608
  u32* h32  = (u32*)(ws + 159383552UL);           //   1,048,576  h packed (hi|lo) [2][128][1024]
  float* cf = (float*)(ws + 160432128UL);         //     524,288  c state fp32 [128][1024]
  u32* flg  = (u32*)(ws + 160956416UL);           //      16,388  flags[256*16] + release

  conv_x_kernel<<<8192, 256, 0, stream>>>(x, xh, xl);
  tsplit_kernel<<<2048, 256, 0, stream>>>(kern, kh, kl, 512);
  tsplit_kernel<<<4096, 256, 0, stream>>>(rker, rh, rl, 1024);
  init_kernel<<<1, 256, 0, stream>>>(flg);

  for (int c = 0; c < NCHUNK; ++c) {
    gemm1_kernel<<<dim3(32, 32), 256, 0, stream>>>(xh, xl, kh, kl, bias, xz, c);
    void* sargs[7];
    int cv = c;
    sargs[0] = (void*)&xz;
    sargs[1] = (void*)&rh;
    sargs[2] = (void*)&rl;
    sargs[3] = (void*)&h32;
    sargs[4] = (void*)&cf;
    sargs[5] = (void*)&flg;
    sargs[6] = (void*)&cv;
    hipLaunchCooperativeKernel((const void*)lstm_scan_kernel, dim3(256), dim3(256),
                               sargs, 0u, stream);
  }
  cls_kernel<<<128, 256, 0, stream>>>(h32, wcls, bcls, out);
}

// Round 6
// 4270.066 us; speedup vs baseline: 1.6223x; 1.3203x over previous
//
#include <hip/hip_runtime.h>

typedef unsigned short u16;
typedef unsigned int u32;
typedef unsigned long long u64;
typedef __attribute__((ext_vector_type(8))) short bf16x8;
typedef __attribute__((ext_vector_type(8))) unsigned short u16x8;
typedef __attribute__((ext_vector_type(4))) float f32x4;

// Problem dims: B=128, T=256, D=512, U=1024, G=4U=4096, C=10
#define TC 32
#define NCHUNK 8

static __device__ __forceinline__ u16 f2bf(float x) {
  union { float f; u32 u; } v; v.f = x;
  u32 r = v.u + 0x7fffu + ((v.u >> 16) & 1u);   // round-to-nearest-even
  return (u16)(r >> 16);
}
static __device__ __forceinline__ float bf2f(u16 h) {
  union { u32 u; float f; } v; v.u = ((u32)h) << 16;
  return v.f;
}
static __device__ __forceinline__ float sigm(float x) {
  return 1.0f / (1.0f + __expf(-x));
}
static __device__ __forceinline__ void gload_lds16(const u16* g, u16* l) {
  __builtin_amdgcn_global_load_lds(
      (const __attribute__((address_space(1))) void*)g,
      (__attribute__((address_space(3))) void*)l, 16, 0, 0);
}

// ---------------- prep: x [B,T,D] f32 -> x_hi/x_lo bf16 [T,B,D] ----------------
__global__ __launch_bounds__(256) void conv_x_kernel(const float* __restrict__ x,
                                                     u16* __restrict__ xh,
                                                     u16* __restrict__ xl) {
  int idx = blockIdx.x * 256 + threadIdx.x;
  size_t i8 = (size_t)idx * 8;
  int b = (int)(i8 >> 17);
  int r = (int)(i8 & 131071);
  int t = r >> 9;
  int d = r & 511;
  const f32x4* s = (const f32x4*)(x + i8);
  f32x4 v0 = s[0], v1 = s[1];
  u16x8 vh, vl;
#pragma unroll
  for (int j = 0; j < 8; ++j) {
    float v = (j < 4) ? v0[j] : v1[j - 4];
    u16 h = f2bf(v);
    vh[j] = h;
    vl[j] = f2bf(v - bf2f(h));
  }
  size_t o = ((size_t)(t * 128 + b)) * 512 + d;
  *(u16x8*)(xh + o) = vh;
  *(u16x8*)(xl + o) = vl;
}

// ------------- prep: weight [K,4096] f32 -> [4096,K] bf16 hi/lo (transposed) -------------
__global__ __launch_bounds__(256) void tsplit_kernel(const float* __restrict__ w,
                                                     u16* __restrict__ oh,
                                                     u16* __restrict__ ol, int K) {
  int idx = blockIdx.x * 256 + threadIdx.x;
  int d = idx >> 10;
  int g4 = (idx & 1023) * 4;
  f32x4 v = *(const f32x4*)(w + (size_t)d * 4096 + g4);
#pragma unroll
  for (int j = 0; j < 4; ++j) {
    int g = g4 + j;
    u16 h = f2bf(v[j]);
    oh[(size_t)g * K + d] = h;
    ol[(size_t)g * K + d] = f2bf(v[j] - bf2f(h));
  }
}

// ------------- GEMM1 (per chunk): xz[(t-c*TC)*128+b][g] = x @ kernel + bias -------------
__global__ __launch_bounds__(256) void gemm1_kernel(const u16* __restrict__ xh,
                                                    const u16* __restrict__ xl,
                                                    const u16* __restrict__ kh,
                                                    const u16* __restrict__ kl,
                                                    const float* __restrict__ bias,
                                                    float* __restrict__ xz, int c) {
  __shared__ u16 Ah[4096], Al[4096], Bh[4096], Bl[4096];
  const int tid = threadIdx.x;
  const int w = tid >> 6, l = tid & 63;
  const int m0w = blockIdx.y * 128;
  const int m0g = c * 4096 + m0w;
  const int n0 = blockIdx.x * 128;
  const int wr = w >> 1, wc = w & 1;
  const int srow = l >> 2, schunk = l & 3;
  const int fr = l & 15, fc = l >> 4;

  f32x4 acc[4][4];
#pragma unroll
  for (int a = 0; a < 4; ++a)
#pragma unroll
    for (int b = 0; b < 4; ++b) acc[a][b] = (f32x4){0.f, 0.f, 0.f, 0.f};

  for (int kt = 0; kt < 16; ++kt) {
    const int koff = kt * 32 + schunk * 8;
#pragma unroll
    for (int i = 0; i < 8; ++i) {
      const int q = w + i * 4;
      const int buf = q >> 3, ch = q & 7;
      const size_t ro = (size_t)(ch * 16 + srow);
      if (buf == 0)      gload_lds16(xh + (m0g + ro) * 512 + koff, Ah + ch * 512);
      else if (buf == 1) gload_lds16(xl + (m0g + ro) * 512 + koff, Al + ch * 512);
      else if (buf == 2) gload_lds16(kh + (n0 + ro) * 512 + koff, Bh + ch * 512);
      else               gload_lds16(kl + (n0 + ro) * 512 + koff, Bl + ch * 512);
    }
    __syncthreads();

    bf16x8 a_h[4], a_l[4], b_h[4], b_l[4];
#pragma unroll
    for (int mf = 0; mf < 4; ++mf) {
      int row = wr * 64 + mf * 16 + fr;
      a_h[mf] = *(const bf16x8*)(Ah + row * 32 + fc * 8);
      a_l[mf] = *(const bf16x8*)(Al + row * 32 + fc * 8);
    }
#pragma unroll
    for (int nf = 0; nf < 4; ++nf) {
      int col = wc * 64 + nf * 16 + fr;
      b_h[nf] = *(const bf16x8*)(Bh + col * 32 + fc * 8);
      b_l[nf] = *(const bf16x8*)(Bl + col * 32 + fc * 8);
    }
#pragma unroll
    for (int mf = 0; mf < 4; ++mf)
#pragma unroll
      for (int nf = 0; nf < 4; ++nf) {
        acc[mf][nf] = __builtin_amdgcn_mfma_f32_16x16x32_bf16(a_h[mf], b_h[nf], acc[mf][nf], 0, 0, 0);
        acc[mf][nf] = __builtin_amdgcn_mfma_f32_16x16x32_bf16(a_h[mf], b_l[nf], acc[mf][nf], 0, 0, 0);
        acc[mf][nf] = __builtin_amdgcn_mfma_f32_16x16x32_bf16(a_l[mf], b_h[nf], acc[mf][nf], 0, 0, 0);
      }
    __syncthreads();
  }

#pragma unroll
  for (int nf = 0; nf < 4; ++nf) {
    const int col = n0 + wc * 64 + nf * 16 + fr;
    const float bv = bias[col];
#pragma unroll
    for (int mf = 0; mf < 4; ++mf) {
      const int rw = m0w + wr * 64 + mf * 16 + fc * 4;
#pragma unroll
      for (int rg = 0; rg < 4; ++rg)
        xz[(size_t)(rw + rg) * 4096 + col] = acc[mf][nf][rg] + bv;
    }
  }
}

// ------------- init: zero barrier flags (ws is 0xAA-poisoned before every launch) -------------
__global__ __launch_bounds__(256) void init_kernel(u32* flags) {
  // flags[blk*16] for blk 0..255; releases at flags[4096 + mi*16]
  for (int i = threadIdx.x; i < 4352; i += 256) flags[i] = 0u;
}

// ------------- persistent LSTM scan, one chunk of TC steps -------------
// 256 blocks (1/CU). Block: mi = blk>>7 (64 batch rows), ui = blk&127 (8 U-cols).
// R slice in LDS (staged once per chunk). c-state in registers.
// h exchanged through global in MFMA-FRAGMENT layout so reads are contiguous:
//   h32[buf][mi][w][ks][lane][j]  (j=0..7 u32, each u32 = hi<<16|lo of one elem)
//   flat u32 idx = buf*131072 + mi*65536 + w*16384 + ks*512 + lane*8 + j
// Reader (wave w, lane l): 32 B contiguous per ks — dense MALL lines (round-5
// profile showed the [row][col] gather cost ~8x transaction amplification).
// Grid barrier: TWO independent halves (mi=0/1) — blocks only depend on their
// own 64 batch rows; fan-in 128, no cross-half jitter. No RMWs.
__global__ __launch_bounds__(256, 1) void lstm_scan_kernel(
    const float* __restrict__ xz,
    const u16* __restrict__ rwh, const u16* __restrict__ rwl,
    u32* __restrict__ h32, float* __restrict__ cf,
    u32* __restrict__ flags, int c) {
  __shared__ u16 Rh[32768];   // [nf 2][ks 32][lane 64][8] = 64KB
  __shared__ u16 Rl[32768];   // 64KB
  const int tid = threadIdx.x;
  const int w = tid >> 6, l = tid & 63;
  const int blk = blockIdx.x;
  const int mi = blk >> 7, ui = blk & 127;

  // stage R fragments once per chunk
  for (int gidx = tid; gidx < 4096; gidx += 256) {
    const int lr = gidx & 63;
    const int ks = (gidx >> 6) & 31;
    const int nf = gidx >> 11;
    const int cc = lr & 15;
    const int kb = ks * 32 + ((lr >> 4) << 3);
    const int gate = nf * 2 + (cc >> 3);
    const size_t gcol = (size_t)(gate * 1024 + ui * 8 + (cc & 7));
    *(u16x8*)(Rh + gidx * 8) = *(const u16x8*)(rwh + gcol * 1024 + kb);
    *(u16x8*)(Rl + gidx * 8) = *(const u16x8*)(rwl + gcol * 1024 + kb);
  }

  const int fr = l & 15, fc = l >> 4;
  const int crow = mi * 64 + w * 16 + fc * 4;    // C rows base (batch index)
  const int uu = ui * 8 + (fr & 7);
  const int gcol0 = ((fr >> 3) ? 1024 : 0) + uu;      // i or f column
  const int gcol1 = ((fr >> 3) ? 3072 : 2048) + uu;   // g or o column

  // reader base (fragment layout): lane-contiguous 32B per ks
  const u32 rbase = mi * 65536 + w * 16384 + l * 8;
  // writer base: element (row=crow+rg, col=uu) ->
  //   lane' = (ui&3)*16 + (fc*4+rg), ks' = ui>>2, j' = fr&7
  const u32 wbase = mi * 65536 + w * 16384 + (u32)(ui >> 2) * 512 +
                    ((u32)(ui & 3) * 16 + (u32)(fc * 4)) * 8 + (u32)(fr & 7);

  float cs[4] = {0.f, 0.f, 0.f, 0.f};
  if (c && fr < 8) {
#pragma unroll
    for (int rg = 0; rg < 4; ++rg) cs[rg] = cf[(size_t)(crow + rg) * 1024 + uu];
  }
  __syncthreads();

  for (int tc = 0; tc < TC; ++tc) {
    const int t = c * TC + tc;
    f32x4 a0 = (f32x4){0.f, 0.f, 0.f, 0.f};
    f32x4 a1 = (f32x4){0.f, 0.f, 0.f, 0.f};
    if (t) {   // global t=0: h=0, z = xz only
      const u32* hp = h32 + ((u32)(t & 1)) * 131072u + rbase;
#pragma unroll 4
      for (int ks = 0; ks < 32; ++ks) {
        const u64* hq = (const u64*)(hp + ks * 512);
        u64 q0 = __hip_atomic_load(hq + 0, __ATOMIC_RELAXED, __HIP_MEMORY_SCOPE_AGENT);
        u64 q1 = __hip_atomic_load(hq + 1, __ATOMIC_RELAXED, __HIP_MEMORY_SCOPE_AGENT);
        u64 q2 = __hip_atomic_load(hq + 2, __ATOMIC_RELAXED, __HIP_MEMORY_SCOPE_AGENT);
        u64 q3 = __hip_atomic_load(hq + 3, __ATOMIC_RELAXED, __HIP_MEMORY_SCOPE_AGENT);
        u32 P0 = (u32)q0, P1 = (u32)(q0 >> 32);
        u32 P2 = (u32)q1, P3 = (u32)(q1 >> 32);
        u32 P4 = (u32)q2, P5 = (u32)(q2 >> 32);
        u32 P6 = (u32)q3, P7 = (u32)(q3 >> 32);
        union { u32 wv[4]; bf16x8 v; } uh, ul;
        uh.wv[0] = __builtin_amdgcn_perm(P1, P0, 0x07060302u);
        ul.wv[0] = __builtin_amdgcn_perm(P1, P0, 0x05040100u);
        uh.wv[1] = __builtin_amdgcn_perm(P3, P2, 0x07060302u);
        ul.wv[1] = __builtin_amdgcn_perm(P3, P2, 0x05040100u);
        uh.wv[2] = __builtin_amdgcn_perm(P5, P4, 0x07060302u);
        ul.wv[2] = __builtin_amdgcn_perm(P5, P4, 0x05040100u);
        uh.wv[3] = __builtin_amdgcn_perm(P7, P6, 0x07060302u);
        ul.wv[3] = __builtin_amdgcn_perm(P7, P6, 0x05040100u);
        bf16x8 b0h = *(const bf16x8*)(Rh + (ks * 64 + l) * 8);
        bf16x8 b0l = *(const bf16x8*)(Rl + (ks * 64 + l) * 8);
        bf16x8 b1h = *(const bf16x8*)(Rh + ((32 + ks) * 64 + l) * 8);
        bf16x8 b1l = *(const bf16x8*)(Rl + ((32 + ks) * 64 + l) * 8);
        a0 = __builtin_amdgcn_mfma_f32_16x16x32_bf16(uh.v, b0h, a0, 0, 0, 0);
        a0 = __builtin_amdgcn_mfma_f32_16x16x32_bf16(uh.v, b0l, a0, 0, 0, 0);
        a0 = __builtin_amdgcn_mfma_f32_16x16x32_bf16(ul.v, b0h, a0, 0, 0, 0);
        a1 = __builtin_amdgcn_mfma_f32_16x16x32_bf16(uh.v, b1h, a1, 0, 0, 0);
        a1 = __builtin_amdgcn_mfma_f32_16x16x32_bf16(uh.v, b1l, a1, 0, 0, 0);
        a1 = __builtin_amdgcn_mfma_f32_16x16x32_bf16(ul.v, b1h, a1, 0, 0, 0);
      }
    }
    const float* xzt = xz + ((size_t)tc << 19);  // tc * 128 * 4096
    float z0[4], z1[4];
#pragma unroll
    for (int rg = 0; rg < 4; ++rg) {
      z0[rg] = a0[rg] + xzt[(size_t)(crow + rg) * 4096 + gcol0];
      z1[rg] = a1[rg] + xzt[(size_t)(crow + rg) * 4096 + gcol1];
    }
    u32* wp = h32 + ((u32)((t + 1) & 1)) * 131072u + wbase;
#pragma unroll
    for (int rg = 0; rg < 4; ++rg) {
      float p0 = __shfl_xor(z0[rg], 8, 64);      // pair (i,f) / (g,o) lanes
      float p1 = __shfl_xor(z1[rg], 8, 64);
      if (fr < 8) {
        float ig = sigm(z0[rg]);
        float fg = sigm(p0);
        float gg = tanhf(z1[rg]);
        float og = sigm(p1);
        float cn = fg * cs[rg] + ig * gg;
        cs[rg] = cn;
        float hv = og * tanhf(cn);
        u16 hi = f2bf(hv);
        u16 lo = f2bf(hv - bf2f(hi));
        u32 P = ((u32)hi << 16) | (u32)lo;
        __hip_atomic_store(wp + rg * 8, P,
                           __ATOMIC_RELAXED, __HIP_MEMORY_SCOPE_AGENT);
      }
    }
    // ---- per-half grid barrier (fan-in 128, monotonic, no RMW) ----
    const u32 tgt = (u32)(t + 1);
    asm volatile("s_waitcnt vmcnt(0)" ::: "memory");   // h stores reached MALL
    __syncthreads();
    u32* release = flags + 4096 + mi * 16;
    if (ui == 0) {
      if (tid == 0)
        __hip_atomic_store(flags + blk * 16, tgt, __ATOMIC_RELAXED, __HIP_MEMORY_SCOPE_AGENT);
      if (tid < 128) {   // poll this half's 128 flags (distinct 64B lines)
        const u32* f = flags + (mi * 128 + tid) * 16;
        for (int g = 0; g < (1 << 18); ++g) {
          if (__hip_atomic_load(f, __ATOMIC_RELAXED, __HIP_MEMORY_SCOPE_AGENT) >= tgt) break;
        }
      }
      __syncthreads();
      if (tid == 0)
        __hip_atomic_store(release, tgt, __ATOMIC_RELAXED, __HIP_MEMORY_SCOPE_AGENT);
    } else {
      if (tid == 0) {
        __hip_atomic_store(flags + blk * 16, tgt, __ATOMIC_RELAXED, __HIP_MEMORY_SCOPE_AGENT);
        for (int g = 0; g < (1 << 18); ++g) {
          if (__hip_atomic_load(release, __ATOMIC_RELAXED, __HIP_MEMORY_SCOPE_AGENT) >= tgt) break;
          __builtin_amdgcn_s_sleep(1);
        }
      }
      __syncthreads();
    }
  }

  if (fr < 8) {
#pragma unroll
    for (int rg = 0; rg < 4; ++rg) cf[(size_t)(crow + rg) * 1024 + uu] = cs[rg];
  }
}

// ------------- classifier + softmax: one block per batch row -------------
// h_last is in buffer 0, FRAGMENT layout: idx = mi*65536 + w*16384 + ks*512 + lane*8 + j
__global__ __launch_bounds__(256) void cls_kernel(const u32* __restrict__ h32,
                                                  const float* __restrict__ wcls,
                                                  const float* __restrict__ bcls,
                                                  float* __restrict__ out) {
  __shared__ float red[2560];
  const int tid = threadIdx.x;
  const int row = blockIdx.x;
  const int rmi = row >> 6, rw = (row >> 4) & 3, lr = row & 15;
  const u32 rb = (u32)rmi * 65536u + (u32)rw * 16384u;
  float acc[10];
#pragma unroll
  for (int cc = 0; cc < 10; ++cc) acc[cc] = 0.f;
  const int k0 = tid * 4;
  for (int k = k0; k < k0 + 4; ++k) {
    const int ks = k >> 5, hi2 = (k >> 3) & 3, j = k & 7;
    u32 P = h32[rb + (u32)ks * 512u + ((u32)hi2 * 16u + (u32)lr) * 8u + (u32)j];
    float hv = bf2f((u16)(P >> 16)) + bf2f((u16)(P & 0xffffu));
#pragma unroll
    for (int cc = 0; cc < 10; ++cc) acc[cc] += hv * wcls[(size_t)k * 10 + cc];
  }
#pragma unroll
  for (int cc = 0; cc < 10; ++cc) red[tid * 10 + cc] = acc[cc];
  __syncthreads();
  for (int s = 128; s >= 1; s >>= 1) {
    if (tid < s) {
#pragma unroll
      for (int cc = 0; cc < 10; ++cc) red[tid * 10 + cc] += red[(tid + s) * 10 + cc];
    }
    __syncthreads();
  }
  if (tid == 0) {
    float lg[10];
    float m = -1e30f;
#pragma unroll
    for (int cc = 0; cc < 10; ++cc) { lg[cc] = red[cc] + bcls[cc]; m = fmaxf(m, lg[cc]); }
    float ssum = 0.f;
#pragma unroll
    for (int cc = 0; cc < 10; ++cc) { lg[cc] = __expf(lg[cc] - m); ssum += lg[cc]; }
    float inv = 1.f / ssum;
#pragma unroll
    for (int cc = 0; cc < 10; ++cc) out[row * 10 + cc] = lg[cc] * inv;
  }
}

// ---------------- host ----------------
extern "C" void kernel_launch(void* const* d_in, const int* in_sizes, int n_in,
                              void* d_out, int out_size, void* d_ws, size_t ws_size,
                              hipStream_t stream) {
  const float* x    = (const float*)d_in[0];
  const float* kern = (const float*)d_in[1];
  const float* rker = (const float*)d_in[2];
  const float* bias = (const float*)d_in[3];
  const float* wcls = (const float*)d_in[4];
  const float* bcls = (const float*)d_in[5];
  float* out = (float*)d_out;
  char* ws = (char*)d_ws;

  // workspace layout (bytes) — total ~161.0 MB
  float* xz = (float*)(ws + 0UL);                 //  67,108,864  xz chunk fp32 [TC][128][4096]
  u16* xh   = (u16*)(ws + 67108864UL);            //  33,554,432  x hi bf16 [T*128][512]
  u16* xl   = (u16*)(ws + 100663296UL);           //  33,554,432
  u16* kh   = (u16*)(ws + 134217728UL);           //   4,194,304  kernel^T hi [4096][512]
  u16* kl   = (u16*)(ws + 138412032UL);           //   4,194,304
  u16* rh   = (u16*)(ws + 142606336UL);           //   8,388,608  R^T hi [4096][1024]
  u16* rl   = (u16*)(ws + 150994944UL);           //   8,388,608
  u32* h32  = (u32*)(ws + 159383552UL);           //   1,048,576  h packed frag-layout [2][2][4][32][64][8]
  float* cf = (float*)(ws + 160432128UL);         //     524,288  c state fp32 [128][1024]
  u32* flg  = (u32*)(ws + 160956416UL);           //      17,408  flags[256*16] + releases

  conv_x_kernel<<<8192, 256, 0, stream>>>(x, xh, xl);
  tsplit_kernel<<<2048, 256, 0, stream>>>(kern, kh, kl, 512);
  tsplit_kernel<<<4096, 256, 0, stream>>>(rker, rh, rl, 1024);
  init_kernel<<<1, 256, 0, stream>>>(flg);

  for (int c = 0; c < NCHUNK; ++c) {
    gemm1_kernel<<<dim3(32, 32), 256, 0, stream>>>(xh, xl, kh, kl, bias, xz, c);
    void* sargs[7];
    int cv = c;
    sargs[0] = (void*)&xz;
    sargs[1] = (void*)&rh;
    sargs[2] = (void*)&rl;
    sargs[3] = (void*)&h32;
    sargs[4] = (void*)&cf;
    sargs[5] = (void*)&flg;
    sargs[6] = (void*)&cv;
    hipLaunchCooperativeKernel((const void*)lstm_scan_kernel, dim3(256), dim3(256),
                               sargs, 0u, stream);
  }
  cls_kernel<<<128, 256, 0, stream>>>(h32, wcls, bcls, out);
}

// Round 7
// 4048.825 us; speedup vs baseline: 1.7110x; 1.0546x over previous
//
#include <hip/hip_runtime.h>

typedef unsigned short u16;
typedef unsigned int u32;
typedef unsigned long long u64;
typedef __attribute__((ext_vector_type(8))) short bf16x8;
typedef __attribute__((ext_vector_type(8))) unsigned short u16x8;
typedef __attribute__((ext_vector_type(4))) float f32x4;

// Problem dims: B=128, T=256, D=512, U=1024, G=4U=4096, C=10
#define TC 32
#define NCHUNK 8

static __device__ __forceinline__ u16 f2bf(float x) {
  union { float f; u32 u; } v; v.f = x;
  u32 r = v.u + 0x7fffu + ((v.u >> 16) & 1u);   // round-to-nearest-even
  return (u16)(r >> 16);
}
static __device__ __forceinline__ float bf2f(u16 h) {
  union { u32 u; float f; } v; v.u = ((u32)h) << 16;
  return v.f;
}
static __device__ __forceinline__ float sigm(float x) {
  return 1.0f / (1.0f + __expf(-x));
}
static __device__ __forceinline__ void gload_lds16(const u16* g, u16* l) {
  __builtin_amdgcn_global_load_lds(
      (const __attribute__((address_space(1))) void*)g,
      (__attribute__((address_space(3))) void*)l, 16, 0, 0);
}

// ---------------- prep: x [B,T,D] f32 -> x_hi/x_lo bf16 [T,B,D] ----------------
__global__ __launch_bounds__(256) void conv_x_kernel(const float* __restrict__ x,
                                                     u16* __restrict__ xh,
                                                     u16* __restrict__ xl) {
  int idx = blockIdx.x * 256 + threadIdx.x;
  size_t i8 = (size_t)idx * 8;
  int b = (int)(i8 >> 17);
  int r = (int)(i8 & 131071);
  int t = r >> 9;
  int d = r & 511;
  const f32x4* s = (const f32x4*)(x + i8);
  f32x4 v0 = s[0], v1 = s[1];
  u16x8 vh, vl;
#pragma unroll
  for (int j = 0; j < 8; ++j) {
    float v = (j < 4) ? v0[j] : v1[j - 4];
    u16 h = f2bf(v);
    vh[j] = h;
    vl[j] = f2bf(v - bf2f(h));
  }
  size_t o = ((size_t)(t * 128 + b)) * 512 + d;
  *(u16x8*)(xh + o) = vh;
  *(u16x8*)(xl + o) = vl;
}

// ------------- prep: weight [K,4096] f32 -> [4096,K] bf16 hi/lo (transposed) -------------
__global__ __launch_bounds__(256) void tsplit_kernel(const float* __restrict__ w,
                                                     u16* __restrict__ oh,
                                                     u16* __restrict__ ol, int K) {
  int idx = blockIdx.x * 256 + threadIdx.x;
  int d = idx >> 10;
  int g4 = (idx & 1023) * 4;
  f32x4 v = *(const f32x4*)(w + (size_t)d * 4096 + g4);
#pragma unroll
  for (int j = 0; j < 4; ++j) {
    int g = g4 + j;
    u16 h = f2bf(v[j]);
    oh[(size_t)g * K + d] = h;
    ol[(size_t)g * K + d] = f2bf(v[j] - bf2f(h));
  }
}

// ------------- GEMM1 (per chunk): xz[(t-c*TC)*128+b][g] = x @ kernel + bias -------------
__global__ __launch_bounds__(256) void gemm1_kernel(const u16* __restrict__ xh,
                                                    const u16* __restrict__ xl,
                                                    const u16* __restrict__ kh,
                                                    const u16* __restrict__ kl,
                                                    const float* __restrict__ bias,
                                                    float* __restrict__ xz, int c) {
  __shared__ u16 Ah[4096], Al[4096], Bh[4096], Bl[4096];
  const int tid = threadIdx.x;
  const int w = tid >> 6, l = tid & 63;
  const int m0w = blockIdx.y * 128;
  const int m0g = c * 4096 + m0w;
  const int n0 = blockIdx.x * 128;
  const int wr = w >> 1, wc = w & 1;
  const int srow = l >> 2, schunk = l & 3;
  const int fr = l & 15, fc = l >> 4;

  f32x4 acc[4][4];
#pragma unroll
  for (int a = 0; a < 4; ++a)
#pragma unroll
    for (int b = 0; b < 4; ++b) acc[a][b] = (f32x4){0.f, 0.f, 0.f, 0.f};

  for (int kt = 0; kt < 16; ++kt) {
    const int koff = kt * 32 + schunk * 8;
#pragma unroll
    for (int i = 0; i < 8; ++i) {
      const int q = w + i * 4;
      const int buf = q >> 3, ch = q & 7;
      const size_t ro = (size_t)(ch * 16 + srow);
      if (buf == 0)      gload_lds16(xh + (m0g + ro) * 512 + koff, Ah + ch * 512);
      else if (buf == 1) gload_lds16(xl + (m0g + ro) * 512 + koff, Al + ch * 512);
      else if (buf == 2) gload_lds16(kh + (n0 + ro) * 512 + koff, Bh + ch * 512);
      else               gload_lds16(kl + (n0 + ro) * 512 + koff, Bl + ch * 512);
    }
    __syncthreads();

    bf16x8 a_h[4], a_l[4], b_h[4], b_l[4];
#pragma unroll
    for (int mf = 0; mf < 4; ++mf) {
      int row = wr * 64 + mf * 16 + fr;
      a_h[mf] = *(const bf16x8*)(Ah + row * 32 + fc * 8);
      a_l[mf] = *(const bf16x8*)(Al + row * 32 + fc * 8);
    }
#pragma unroll
    for (int nf = 0; nf < 4; ++nf) {
      int col = wc * 64 + nf * 16 + fr;
      b_h[nf] = *(const bf16x8*)(Bh + col * 32 + fc * 8);
      b_l[nf] = *(const bf16x8*)(Bl + col * 32 + fc * 8);
    }
#pragma unroll
    for (int mf = 0; mf < 4; ++mf)
#pragma unroll
      for (int nf = 0; nf < 4; ++nf) {
        acc[mf][nf] = __builtin_amdgcn_mfma_f32_16x16x32_bf16(a_h[mf], b_h[nf], acc[mf][nf], 0, 0, 0);
        acc[mf][nf] = __builtin_amdgcn_mfma_f32_16x16x32_bf16(a_h[mf], b_l[nf], acc[mf][nf], 0, 0, 0);
        acc[mf][nf] = __builtin_amdgcn_mfma_f32_16x16x32_bf16(a_l[mf], b_h[nf], acc[mf][nf], 0, 0, 0);
      }
    __syncthreads();
  }

#pragma unroll
  for (int nf = 0; nf < 4; ++nf) {
    const int col = n0 + wc * 64 + nf * 16 + fr;
    const float bv = bias[col];
#pragma unroll
    for (int mf = 0; mf < 4; ++mf) {
      const int rw = m0w + wr * 64 + mf * 16 + fc * 4;
#pragma unroll
      for (int rg = 0; rg < 4; ++rg)
        xz[(size_t)(rw + rg) * 4096 + col] = acc[mf][nf][rg] + bv;
    }
  }
}

// ------------- init: zero barrier flags (ws is 0xAA-poisoned before every launch) -------------
__global__ __launch_bounds__(256) void init_kernel(u32* flags) {
  // flags[blk*16] for blk 0..255; releases at flags[4096 + mi*16]
  for (int i = threadIdx.x; i < 4352; i += 256) flags[i] = 0u;
}

// ------------- persistent LSTM scan, one chunk of TC steps -------------
// 256 blocks (1/CU). Block: mi = blk>>7 (64 batch rows), ui = blk&127 (8 U-cols).
// R slice in LDS (staged once per chunk). c-state in registers.
// h stored as PLAIN bf16 (hi only) in MFMA-fragment layout:
//   h16[buf][mi][w][ks][lane][j]  (j=0..7 u16)
//   flat u16 idx = buf*131072 + mi*65536 + w*16384 + ks*512 + lane*8 + j
// Recurrent matmul: z += h_hi x R_hi + h_hi x R_lo  (the h_lo x R_hi term is
// dropped — error analysis: adds ~1e-4 rms z-noise/step, damped by contractive
// gates to ~3e-5 at output, 16x under headroom). Halves h MALL traffic (64->32
// MB/step) and cuts MFMA 192->128/wave, removes all v_perm unpacking.
// Grid barrier: two independent halves (mi=0/1), flag array + release, no RMW.
__global__ __launch_bounds__(256, 1) void lstm_scan_kernel(
    const float* __restrict__ xz,
    const u16* __restrict__ rwh, const u16* __restrict__ rwl,
    u16* __restrict__ h16, float* __restrict__ cf,
    u32* __restrict__ flags, int c) {
  __shared__ u16 Rh[32768];   // [nf 2][ks 32][lane 64][8] = 64KB
  __shared__ u16 Rl[32768];   // 64KB
  const int tid = threadIdx.x;
  const int w = tid >> 6, l = tid & 63;
  const int blk = blockIdx.x;
  const int mi = blk >> 7, ui = blk & 127;

  // stage R fragments once per chunk
  for (int gidx = tid; gidx < 4096; gidx += 256) {
    const int lr = gidx & 63;
    const int ks = (gidx >> 6) & 31;
    const int nf = gidx >> 11;
    const int cc = lr & 15;
    const int kb = ks * 32 + ((lr >> 4) << 3);
    const int gate = nf * 2 + (cc >> 3);
    const size_t gcol = (size_t)(gate * 1024 + ui * 8 + (cc & 7));
    *(u16x8*)(Rh + gidx * 8) = *(const u16x8*)(rwh + gcol * 1024 + kb);
    *(u16x8*)(Rl + gidx * 8) = *(const u16x8*)(rwl + gcol * 1024 + kb);
  }

  const int fr = l & 15, fc = l >> 4;
  const int crow = mi * 64 + w * 16 + fc * 4;    // C rows base (batch index)
  const int uu = ui * 8 + (fr & 7);
  const int gcol0 = ((fr >> 3) ? 1024 : 0) + uu;      // i or f column
  const int gcol1 = ((fr >> 3) ? 3072 : 2048) + uu;   // g or o column

  // reader base (fragment layout): lane-contiguous 16B per ks
  const u32 rbase = mi * 65536 + w * 16384 + l * 8;
  // writer base: element (row=crow+rg, col=uu) ->
  //   lane' = (ui&3)*16 + (fc*4+rg), ks' = ui>>2, j' = fr&7
  const u32 wbase = mi * 65536 + w * 16384 + (u32)(ui >> 2) * 512 +
                    ((u32)(ui & 3) * 16 + (u32)(fc * 4)) * 8 + (u32)(fr & 7);

  float cs[4] = {0.f, 0.f, 0.f, 0.f};
  if (c && fr < 8) {
#pragma unroll
    for (int rg = 0; rg < 4; ++rg) cs[rg] = cf[(size_t)(crow + rg) * 1024 + uu];
  }
  __syncthreads();

  for (int tc = 0; tc < TC; ++tc) {
    const int t = c * TC + tc;
    // xz prefetch (independent of h) — issue before the latency-bound h loop
    const float* xzt = xz + ((size_t)tc << 19);  // tc * 128 * 4096
    float xv0[4], xv1[4];
#pragma unroll
    for (int rg = 0; rg < 4; ++rg) {
      xv0[rg] = xzt[(size_t)(crow + rg) * 4096 + gcol0];
      xv1[rg] = xzt[(size_t)(crow + rg) * 4096 + gcol1];
    }
    f32x4 a0 = (f32x4){0.f, 0.f, 0.f, 0.f};
    f32x4 a1 = (f32x4){0.f, 0.f, 0.f, 0.f};
    if (t) {   // global t=0: h=0, z = xz only
      const u16* hp = h16 + ((u32)(t & 1)) * 131072u + rbase;
#pragma unroll 4
      for (int ks = 0; ks < 32; ++ks) {
        const u64* hq = (const u64*)(hp + ks * 512);
        union { u64 q[2]; bf16x8 v; } ah;
        ah.q[0] = __hip_atomic_load(hq + 0, __ATOMIC_RELAXED, __HIP_MEMORY_SCOPE_AGENT);
        ah.q[1] = __hip_atomic_load(hq + 1, __ATOMIC_RELAXED, __HIP_MEMORY_SCOPE_AGENT);
        bf16x8 b0h = *(const bf16x8*)(Rh + (ks * 64 + l) * 8);
        bf16x8 b0l = *(const bf16x8*)(Rl + (ks * 64 + l) * 8);
        bf16x8 b1h = *(const bf16x8*)(Rh + ((32 + ks) * 64 + l) * 8);
        bf16x8 b1l = *(const bf16x8*)(Rl + ((32 + ks) * 64 + l) * 8);
        a0 = __builtin_amdgcn_mfma_f32_16x16x32_bf16(ah.v, b0h, a0, 0, 0, 0);
        a0 = __builtin_amdgcn_mfma_f32_16x16x32_bf16(ah.v, b0l, a0, 0, 0, 0);
        a1 = __builtin_amdgcn_mfma_f32_16x16x32_bf16(ah.v, b1h, a1, 0, 0, 0);
        a1 = __builtin_amdgcn_mfma_f32_16x16x32_bf16(ah.v, b1l, a1, 0, 0, 0);
      }
    }
    float z0[4], z1[4];
#pragma unroll
    for (int rg = 0; rg < 4; ++rg) {
      z0[rg] = a0[rg] + xv0[rg];
      z1[rg] = a1[rg] + xv1[rg];
    }
    u16* wp = h16 + ((u32)((t + 1) & 1)) * 131072u + wbase;
#pragma unroll
    for (int rg = 0; rg < 4; ++rg) {
      float p0 = __shfl_xor(z0[rg], 8, 64);      // pair (i,f) / (g,o) lanes
      float p1 = __shfl_xor(z1[rg], 8, 64);
      if (fr < 8) {
        float ig = sigm(z0[rg]);
        float fg = sigm(p0);
        float gg = tanhf(z1[rg]);
        float og = sigm(p1);
        float cn = fg * cs[rg] + ig * gg;
        cs[rg] = cn;
        float hv = og * tanhf(cn);
        __hip_atomic_store(wp + rg * 8, f2bf(hv),
                           __ATOMIC_RELAXED, __HIP_MEMORY_SCOPE_AGENT);
      }
    }
    // ---- per-half grid barrier (fan-in 128, monotonic, no RMW) ----
    const u32 tgt = (u32)(t + 1);
    asm volatile("s_waitcnt vmcnt(0)" ::: "memory");   // h stores reached MALL
    __syncthreads();
    u32* release = flags + 4096 + mi * 16;
    if (ui == 0) {
      if (tid == 0)
        __hip_atomic_store(flags + blk * 16, tgt, __ATOMIC_RELAXED, __HIP_MEMORY_SCOPE_AGENT);
      if (tid < 128) {   // poll this half's 128 flags (distinct 64B lines)
        const u32* f = flags + (mi * 128 + tid) * 16;
        for (int g = 0; g < (1 << 18); ++g) {
          if (__hip_atomic_load(f, __ATOMIC_RELAXED, __HIP_MEMORY_SCOPE_AGENT) >= tgt) break;
        }
      }
      __syncthreads();
      if (tid == 0)
        __hip_atomic_store(release, tgt, __ATOMIC_RELAXED, __HIP_MEMORY_SCOPE_AGENT);
    } else {
      if (tid == 0) {
        __hip_atomic_store(flags + blk * 16, tgt, __ATOMIC_RELAXED, __HIP_MEMORY_SCOPE_AGENT);
        for (int g = 0; g < (1 << 18); ++g) {
          if (__hip_atomic_load(release, __ATOMIC_RELAXED, __HIP_MEMORY_SCOPE_AGENT) >= tgt) break;
          __builtin_amdgcn_s_sleep(1);
        }
      }
      __syncthreads();
    }
  }

  if (fr < 8) {
#pragma unroll
    for (int rg = 0; rg < 4; ++rg) cf[(size_t)(crow + rg) * 1024 + uu] = cs[rg];
  }
}

// ------------- classifier + softmax: one block per batch row -------------
// h_last is in buffer 0, FRAGMENT layout: idx = mi*65536 + w*16384 + ks*512 + lane*8 + j
__global__ __launch_bounds__(256) void cls_kernel(const u16* __restrict__ h16,
                                                  const float* __restrict__ wcls,
                                                  const float* __restrict__ bcls,
                                                  float* __restrict__ out) {
  __shared__ float red[2560];
  const int tid = threadIdx.x;
  const int row = blockIdx.x;
  const int rmi = row >> 6, rw = (row >> 4) & 3, lr = row & 15;
  const u32 rb = (u32)rmi * 65536u + (u32)rw * 16384u;
  float acc[10];
#pragma unroll
  for (int cc = 0; cc < 10; ++cc) acc[cc] = 0.f;
  const int k0 = tid * 4;
  for (int k = k0; k < k0 + 4; ++k) {
    const int ks = k >> 5, hi2 = (k >> 3) & 3, j = k & 7;
    u16 P = h16[rb + (u32)ks * 512u + ((u32)hi2 * 16u + (u32)lr) * 8u + (u32)j];
    float hv = bf2f(P);
#pragma unroll
    for (int cc = 0; cc < 10; ++cc) acc[cc] += hv * wcls[(size_t)k * 10 + cc];
  }
#pragma unroll
  for (int cc = 0; cc < 10; ++cc) red[tid * 10 + cc] = acc[cc];
  __syncthreads();
  for (int s = 128; s >= 1; s >>= 1) {
    if (tid < s) {
#pragma unroll
      for (int cc = 0; cc < 10; ++cc) red[tid * 10 + cc] += red[(tid + s) * 10 + cc];
    }
    __syncthreads();
  }
  if (tid == 0) {
    float lg[10];
    float m = -1e30f;
#pragma unroll
    for (int cc = 0; cc < 10; ++cc) { lg[cc] = red[cc] + bcls[cc]; m = fmaxf(m, lg[cc]); }
    float ssum = 0.f;
#pragma unroll
    for (int cc = 0; cc < 10; ++cc) { lg[cc] = __expf(lg[cc] - m); ssum += lg[cc]; }
    float inv = 1.f / ssum;
#pragma unroll
    for (int cc = 0; cc < 10; ++cc) out[row * 10 + cc] = lg[cc] * inv;
  }
}

// ---------------- host ----------------
extern "C" void kernel_launch(void* const* d_in, const int* in_sizes, int n_in,
                              void* d_out, int out_size, void* d_ws, size_t ws_size,
                              hipStream_t stream) {
  const float* x    = (const float*)d_in[0];
  const float* kern = (const float*)d_in[1];
  const float* rker = (const float*)d_in[2];
  const float* bias = (const float*)d_in[3];
  const float* wcls = (const float*)d_in[4];
  const float* bcls = (const float*)d_in[5];
  float* out = (float*)d_out;
  char* ws = (char*)d_ws;

  // workspace layout (bytes) — total ~160.5 MB
  float* xz = (float*)(ws + 0UL);                 //  67,108,864  xz chunk fp32 [TC][128][4096]
  u16* xh   = (u16*)(ws + 67108864UL);            //  33,554,432  x hi bf16 [T*128][512]
  u16* xl   = (u16*)(ws + 100663296UL);           //  33,554,432
  u16* kh   = (u16*)(ws + 134217728UL);           //   4,194,304  kernel^T hi [4096][512]
  u16* kl   = (u16*)(ws + 138412032UL);           //   4,194,304
  u16* rh   = (u16*)(ws + 142606336UL);           //   8,388,608  R^T hi [4096][1024]
  u16* rl   = (u16*)(ws + 150994944UL);           //   8,388,608
  u16* h16  = (u16*)(ws + 159383552UL);           //     524,288  h bf16 frag-layout [2][2][4][32][64][8]
  float* cf = (float*)(ws + 159907840UL);         //     524,288  c state fp32 [128][1024]
  u32* flg  = (u32*)(ws + 160432128UL);           //      17,408  flags[256*16] + releases

  conv_x_kernel<<<8192, 256, 0, stream>>>(x, xh, xl);
  tsplit_kernel<<<2048, 256, 0, stream>>>(kern, kh, kl, 512);
  tsplit_kernel<<<4096, 256, 0, stream>>>(rker, rh, rl, 1024);
  init_kernel<<<1, 256, 0, stream>>>(flg);

  for (int c = 0; c < NCHUNK; ++c) {
    gemm1_kernel<<<dim3(32, 32), 256, 0, stream>>>(xh, xl, kh, kl, bias, xz, c);
    void* sargs[7];
    int cv = c;
    sargs[0] = (void*)&xz;
    sargs[1] = (void*)&rh;
    sargs[2] = (void*)&rl;
    sargs[3] = (void*)&h16;
    sargs[4] = (void*)&cf;
    sargs[5] = (void*)&flg;
    sargs[6] = (void*)&cv;
    hipLaunchCooperativeKernel((const void*)lstm_scan_kernel, dim3(256), dim3(256),
                               sargs, 0u, stream);
  }
  cls_kernel<<<128, 256, 0, stream>>>(h16, wcls, bcls, out);
}